// Round 8
// baseline (862.973 us; speedup 1.0000x reference)
//
#include <hip/hip_runtime.h>
#include <cfloat>

#define DIM_IN 256
#define HIDDEN 32
#define NE 64
#define ECH 8
#define BLOCK 256

typedef float f32x4 __attribute__((ext_vector_type(4)));

// One token per thread, VGPR<=64 target -> 8 waves/SIMD (R7 lesson: occupancy
// halves past 64 VGPR; launch_bounds(256,8) pins the allocator to 64).
// Latency hiding comes from TLP, not per-wave prefetch. No LDS at all:
// output rows are redistributed with __shfl so each wave stores 1KB
// contiguous (full 64B lines) per instruction. Weights are read with
// wave-uniform indices -> s_load on the scalar pipe. x is read nontemporal
// (zero reuse; one full 64B line per lane per group). Straight-line code:
// no lambdas, no rotating buffers (R5/R6 spill lessons).
__launch_bounds__(BLOCK, 8)
__global__ void router_fwd(const float* __restrict__ x,
                           const float* __restrict__ W1,
                           const float* __restrict__ b1,
                           const float* __restrict__ W2,
                           const float* __restrict__ b2,
                           float* __restrict__ out, int n) {
  const int tid = threadIdx.x;
  const long t = (long)blockIdx.x * BLOCK + tid;
  const bool av = t < n;

  const f32x4* __restrict__ xr =
      reinterpret_cast<const f32x4*>(x + (av ? t : 0) * (long)DIM_IN);

  float h[HIDDEN];
#pragma unroll
  for (int j = 0; j < HIDDEN; ++j) h[j] = 0.0f;

  // ---- layer 1: h = x @ W1, 16 rows (one 64B x-line) per iteration ----
#pragma unroll 1
  for (int g = 0; g < 16; ++g) {
    const f32x4 q0 = __builtin_nontemporal_load(xr + g * 4 + 0);
    const f32x4 q1 = __builtin_nontemporal_load(xr + g * 4 + 1);
    const f32x4 q2 = __builtin_nontemporal_load(xr + g * 4 + 2);
    const f32x4 q3 = __builtin_nontemporal_load(xr + g * 4 + 3);
    const float xs[16] = {q0.x, q0.y, q0.z, q0.w, q1.x, q1.y, q1.z, q1.w,
                          q2.x, q2.y, q2.z, q2.w, q3.x, q3.y, q3.z, q3.w};
    const float* __restrict__ wbase = W1 + g * 16 * HIDDEN;  // uniform -> s_load
#pragma unroll
    for (int k = 0; k < 16; ++k) {
      const float xv = xs[k];
      const float* __restrict__ wrow = wbase + k * HIDDEN;
#pragma unroll
      for (int j = 0; j < HIDDEN; ++j) h[j] = fmaf(xv, wrow[j], h[j]);
    }
  }

  // bias + tanh.  tanh(v) = 1 - 2/(e^{2v}+1): no inf/inf NaN.
#pragma unroll
  for (int j = 0; j < HIDDEN; ++j) {
    const float v = h[j] + b1[j];
    const float e = __expf(2.0f * v);
    h[j] = 1.0f - 2.0f / (e + 1.0f);
  }

  // ---- layer 2 in 8-expert chunks + online top-2 / exp-sum ----
  float v1 = -FLT_MAX, v2 = -FLT_MAX, S = 0.0f;
  int i1 = 0, i2 = 0;

#pragma unroll 1
  for (int c = 0; c < NE / ECH; ++c) {
    float zc[ECH];
#pragma unroll
    for (int e = 0; e < ECH; ++e) zc[e] = 0.0f;
#pragma unroll
    for (int j = 0; j < HIDDEN; ++j) {
      const float hv = h[j];
      const float* __restrict__ wrow = W2 + j * NE + c * ECH;  // uniform
#pragma unroll
      for (int e = 0; e < ECH; ++e) zc[e] = fmaf(hv, wrow[e], zc[e]);
    }
    const float m_prev = v1;
    // strict '>' ascending scan => ties pick lower index (lax.top_k)
#pragma unroll
    for (int e = 0; e < ECH; ++e) {
      const float v = (zc[e] + b2[c * ECH + e]) * 10.0f;  // /TEMP
      zc[e] = v;
      const int ge = c * ECH + e;
      const bool g1 = v > v1;
      const bool g2 = v > v2;
      v2 = g1 ? v1 : (g2 ? v : v2);
      i2 = g1 ? i1 : (g2 ? ge : i2);
      v1 = g1 ? v : v1;
      i1 = g1 ? ge : i1;
    }
    S *= __expf(m_prev - v1);  // rescale old sum (chunk 0: 0*0=0)
#pragma unroll
    for (int e = 0; e < ECH; ++e) S += __expf(zc[e] - v1);
  }

  const float pa = 1.0f / S;             // p_soft[top1] (exp(0)=1)
  const float pb = __expf(v2 - v1) / S;  // p_soft[top2]
  const float d  = pa + pb + 1e-9f;      // ref renorm formula
  const float oa = av ? pa / d : 0.0f;
  const float ob = av ? pb / d : 0.0f;

  // ---- epilogue: shfl-redistribute -> 1KB contiguous store per wave ----
  // Round m: lanes cover 4 tokens' full 64-float rows. Lane L writes token
  // wbase+m*4+(L>>4), float4-chunk L&15:  addr = rowbase + L*16B (coalesced).
  const int lane = tid & 63;
  const int wv   = tid >> 6;
  const long wbase = (long)blockIdx.x * BLOCK + wv * 64;
  const int e0 = (lane & 15) * 4;
#pragma unroll 1
  for (int m = 0; m < 16; ++m) {
    const int src = m * 4 + (lane >> 4);
    const float soa = __shfl(oa, src);
    const float sob = __shfl(ob, src);
    const int   si1 = __shfl(i1, src);
    const int   si2 = __shfl(i2, src);
    f32x4 v;
    v.x = (e0 + 0 == si1) ? soa : ((e0 + 0 == si2) ? sob : 0.0f);
    v.y = (e0 + 1 == si1) ? soa : ((e0 + 1 == si2) ? sob : 0.0f);
    v.z = (e0 + 2 == si1) ? soa : ((e0 + 2 == si2) ? sob : 0.0f);
    v.w = (e0 + 3 == si1) ? soa : ((e0 + 3 == si2) ? sob : 0.0f);
    const long tok = wbase + m * 4 + (lane >> 4);  // this lane's token
    if (tok < n) {
      f32x4* dst = reinterpret_cast<f32x4*>(out + (wbase + m * 4) * NE) + lane;
      *dst = v;
    }
  }
}

extern "C" void kernel_launch(void* const* d_in, const int* in_sizes, int n_in,
                              void* d_out, int out_size, void* d_ws, size_t ws_size,
                              hipStream_t stream) {
  const float* x  = (const float*)d_in[0];
  const float* W1 = (const float*)d_in[1];
  const float* b1 = (const float*)d_in[2];
  const float* W2 = (const float*)d_in[3];
  const float* b2 = (const float*)d_in[4];
  float* out = (float*)d_out;
  const int n_tokens = in_sizes[0] / DIM_IN;
  const int grid = (n_tokens + BLOCK - 1) / BLOCK;
  hipLaunchKernelGGL(router_fwd, dim3(grid), dim3(BLOCK), 0, stream,
                     x, W1, b1, W2, b2, out, n_tokens);
}

// Round 11
// 463.143 us; speedup vs baseline: 1.8633x; 1.8633x over previous
//
#include <hip/hip_runtime.h>
#include <cfloat>

#define DIM_IN 256
#define HIDDEN 32
#define NE 64
#define ECH 8
#define BLOCK 256

typedef float f32x4 __attribute__((ext_vector_type(4)));

// One token per thread in the proven 4-waves/SIMD regime (<=128 VGPR, no
// spill). Layer-1 = R3's 8-row groups with a TWO-deep lookahead: 4 x 16B
// loads outstanding (~1024cy of FMA cover vs ~900cy HBM latency). Explicit
// named-variable shift only (R5/R6 lesson: no lambdas/rotating buffers).
// Weights: wave-uniform indices -> s_load on the scalar pipe. Epilogue:
// R8's shfl redistribute -> 1KB-contiguous stores per wave (WRITE 445MB vs
// 920MB for 64B-granule transposed stores; sector write-amp avoided).
__launch_bounds__(BLOCK, 4)
__global__ void router_fwd(const float* __restrict__ x,
                           const float* __restrict__ W1,
                           const float* __restrict__ b1,
                           const float* __restrict__ W2,
                           const float* __restrict__ b2,
                           float* __restrict__ out, int n) {
  const int tid = threadIdx.x;
  const long t = (long)blockIdx.x * BLOCK + tid;
  const bool av = t < n;

  const float4* __restrict__ xr =
      reinterpret_cast<const float4*>(x + (av ? t : 0) * (long)DIM_IN);

  float h[HIDDEN];
#pragma unroll
  for (int j = 0; j < HIDDEN; ++j) h[j] = 0.0f;

  // ---- layer 1: h = x @ W1; 8 rows/group, 2-group lookahead ----
  float4 p0 = xr[0], p1 = xr[1];  // group g
  float4 q0 = xr[2], q1 = xr[3];  // group g+1

#pragma unroll 1
  for (int g = 0; g < 32; ++g) {
    const int pg = (g < 30 ? (g + 2) * 2 : 0);  // tail: in-bounds dummy (L1-hot)
    const float4 c0 = xr[pg];
    const float4 c1 = xr[pg + 1];
    const float xs[8] = {p0.x, p0.y, p0.z, p0.w, p1.x, p1.y, p1.z, p1.w};
    const float* __restrict__ wbase = W1 + g * 8 * HIDDEN;  // uniform -> s_load
#pragma unroll
    for (int k = 0; k < 8; ++k) {
      const float xv = xs[k];
      const float* __restrict__ wrow = wbase + k * HIDDEN;
#pragma unroll
      for (int j = 0; j < HIDDEN; ++j) h[j] = fmaf(xv, wrow[j], h[j]);
    }
    p0 = q0; p1 = q1; q0 = c0; q1 = c1;  // shift pipeline
  }

  // bias + tanh.  tanh(v) = 1 - 2/(e^{2v}+1): no inf/inf NaN.
#pragma unroll
  for (int j = 0; j < HIDDEN; ++j) {
    const float v = h[j] + b1[j];
    const float e = __expf(2.0f * v);
    h[j] = 1.0f - 2.0f / (e + 1.0f);
  }

  // ---- layer 2 in 8-expert chunks + online top-2 / exp-sum ----
  float v1 = -FLT_MAX, v2 = -FLT_MAX, S = 0.0f;
  int i1 = 0, i2 = 0;

#pragma unroll 1
  for (int c = 0; c < NE / ECH; ++c) {
    float zc[ECH];
#pragma unroll
    for (int e = 0; e < ECH; ++e) zc[e] = 0.0f;
#pragma unroll
    for (int j = 0; j < HIDDEN; ++j) {
      const float hv = h[j];
      const float* __restrict__ wrow = W2 + j * NE + c * ECH;  // uniform
#pragma unroll
      for (int e = 0; e < ECH; ++e) zc[e] = fmaf(hv, wrow[e], zc[e]);
    }
    const float m_prev = v1;
    // strict '>' ascending scan => ties pick lower index (lax.top_k)
#pragma unroll
    for (int e = 0; e < ECH; ++e) {
      const float v = (zc[e] + b2[c * ECH + e]) * 10.0f;  // /TEMP
      zc[e] = v;
      const int ge = c * ECH + e;
      const bool g1 = v > v1;
      const bool g2 = v > v2;
      v2 = g1 ? v1 : (g2 ? v : v2);
      i2 = g1 ? i1 : (g2 ? ge : i2);
      v1 = g1 ? v : v1;
      i1 = g1 ? ge : i1;
    }
    S *= __expf(m_prev - v1);  // rescale old sum (chunk 0: 0*0=0)
#pragma unroll
    for (int e = 0; e < ECH; ++e) S += __expf(zc[e] - v1);
  }

  const float pa = 1.0f / S;             // p_soft[top1] (exp(0)=1)
  const float pb = __expf(v2 - v1) / S;  // p_soft[top2]
  const float d  = pa + pb + 1e-9f;      // ref renorm formula
  const float oa = av ? pa / d : 0.0f;
  const float ob = av ? pb / d : 0.0f;

  // ---- epilogue: shfl-redistribute -> 1KB contiguous store per wave ----
  const int lane = tid & 63;
  const int wv   = tid >> 6;
  const long twbase = (long)blockIdx.x * BLOCK + wv * 64;
  const int e0 = (lane & 15) * 4;
#pragma unroll 1
  for (int m = 0; m < 16; ++m) {
    const int src = m * 4 + (lane >> 4);
    const float soa = __shfl(oa, src);
    const float sob = __shfl(ob, src);
    const int   si1 = __shfl(i1, src);
    const int   si2 = __shfl(i2, src);
    f32x4 v;
    v.x = (e0 + 0 == si1) ? soa : ((e0 + 0 == si2) ? sob : 0.0f);
    v.y = (e0 + 1 == si1) ? soa : ((e0 + 1 == si2) ? sob : 0.0f);
    v.z = (e0 + 2 == si1) ? soa : ((e0 + 2 == si2) ? sob : 0.0f);
    v.w = (e0 + 3 == si1) ? soa : ((e0 + 3 == si2) ? sob : 0.0f);
    const long tok = twbase + m * 4 + (lane >> 4);  // this lane's token
    if (tok < n) {
      f32x4* dst = reinterpret_cast<f32x4*>(out + (twbase + m * 4) * NE) + lane;
      *dst = v;
    }
  }
}

extern "C" void kernel_launch(void* const* d_in, const int* in_sizes, int n_in,
                              void* d_out, int out_size, void* d_ws, size_t ws_size,
                              hipStream_t stream) {
  const float* x  = (const float*)d_in[0];
  const float* W1 = (const float*)d_in[1];
  const float* b1 = (const float*)d_in[2];
  const float* W2 = (const float*)d_in[3];
  const float* b2 = (const float*)d_in[4];
  float* out = (float*)d_out;
  const int n_tokens = in_sizes[0] / DIM_IN;
  const int grid = (n_tokens + BLOCK - 1) / BLOCK;
  hipLaunchKernelGGL(router_fwd, dim3(grid), dim3(BLOCK), 0, stream,
                     x, W1, b1, W2, b2, out, n_tokens);
}

// Round 12
// 455.113 us; speedup vs baseline: 1.8962x; 1.0176x over previous
//
#include <hip/hip_runtime.h>
#include <cfloat>

#define DIM_IN 256
#define HIDDEN 32
#define NE 64
#define ECH 16
#define BLOCK 256

typedef float f32x4 __attribute__((ext_vector_type(4)));

// R3's exact compute body (proven no-spill, 378us, HBM-bound at ~5.8TB/s
// including write amplification) with ONE change: the LDS-transpose epilogue
// is replaced by R8's wave-shfl redistribute, which R8 measured at WRITE
// 445MB vs 920MB (64B-granule transposed stores suffer ~2x sector write
// amplification). No LDS at all. Weights: wave-uniform indices -> s_load on
// the scalar pipe. Straight-line code, immediate-consume loads (R7/R11
// falsified per-wave lookahead: this kernel is BW-bound, not latency-bound).
__launch_bounds__(BLOCK, 4)
__global__ void router_fwd(const float* __restrict__ x,
                           const float* __restrict__ W1,
                           const float* __restrict__ b1,
                           const float* __restrict__ W2,
                           const float* __restrict__ b2,
                           float* __restrict__ out, int n) {
  const int tid = threadIdx.x;
  const long t = (long)blockIdx.x * BLOCK + tid;
  const bool av = t < n;

  const float4* __restrict__ xr =
      reinterpret_cast<const float4*>(x + (av ? t : 0) * (long)DIM_IN);

  float h[HIDDEN];
#pragma unroll
  for (int j = 0; j < HIDDEN; ++j) h[j] = 0.0f;

  // ---- layer 1: h = x @ W1; 8 rows/group, immediate consume (R3) ----
#pragma unroll 1
  for (int i0 = 0; i0 < DIM_IN; i0 += 8) {
    const float4 xa = xr[i0 / 4];
    const float4 xb = xr[i0 / 4 + 1];
    const float xs[8] = {xa.x, xa.y, xa.z, xa.w, xb.x, xb.y, xb.z, xb.w};
#pragma unroll
    for (int k = 0; k < 8; ++k) {
      const float* __restrict__ wrow = W1 + (i0 + k) * HIDDEN;  // uniform -> s_load
      const float xv = xs[k];
#pragma unroll
      for (int j = 0; j < HIDDEN; ++j) h[j] = fmaf(xv, wrow[j], h[j]);
    }
  }

  // bias + tanh.  tanh(v) = 1 - 2/(e^{2v}+1): no inf/inf NaN.
#pragma unroll
  for (int j = 0; j < HIDDEN; ++j) {
    const float v = h[j] + b1[j];
    const float e = __expf(2.0f * v);
    h[j] = 1.0f - 2.0f / (e + 1.0f);
  }

  // ---- layer 2 in 16-expert chunks + online top-2 / exp-sum (R3) ----
  float v1 = -FLT_MAX, v2 = -FLT_MAX, S = 0.0f;
  int i1 = 0, i2 = 0;

#pragma unroll 1
  for (int c = 0; c < NE / ECH; ++c) {
    float zc[ECH];
#pragma unroll
    for (int e = 0; e < ECH; ++e) zc[e] = 0.0f;
#pragma unroll
    for (int j = 0; j < HIDDEN; ++j) {
      const float hv = h[j];
      const float* __restrict__ wrow = W2 + j * NE + c * ECH;  // uniform
#pragma unroll
      for (int e = 0; e < ECH; ++e) zc[e] = fmaf(hv, wrow[e], zc[e]);
    }
    const float m_prev = v1;
    // strict '>' ascending scan => ties pick lower index (lax.top_k)
#pragma unroll
    for (int e = 0; e < ECH; ++e) {
      const float v = (zc[e] + b2[c * ECH + e]) * 10.0f;  // /TEMP
      zc[e] = v;
      const int ge = c * ECH + e;
      const bool g1 = v > v1;
      const bool g2 = v > v2;
      v2 = g1 ? v1 : (g2 ? v : v2);
      i2 = g1 ? i1 : (g2 ? ge : i2);
      v1 = g1 ? v : v1;
      i1 = g1 ? ge : i1;
    }
    S *= __expf(m_prev - v1);  // rescale old sum (chunk 0: 0*0=0)
#pragma unroll
    for (int e = 0; e < ECH; ++e) S += __expf(zc[e] - v1);
  }

  const float pa = 1.0f / S;             // p_soft[top1] (exp(0)=1)
  const float pb = __expf(v2 - v1) / S;  // p_soft[top2]
  const float d  = pa + pb + 1e-9f;      // ref renorm formula
  const float oa = av ? pa / d : 0.0f;
  const float ob = av ? pb / d : 0.0f;

  // ---- epilogue: shfl-redistribute -> 1KB contiguous store per wave ----
  // Round m covers 4 tokens. Lane L supplies/receives token m*4+(L>>4) and
  // writes float4-chunk (L&15): addr = rowbase + L*16B -> one 1KB burst.
  const int lane = tid & 63;
  const int wv   = tid >> 6;
  const long twbase = (long)blockIdx.x * BLOCK + wv * 64;
  const int e0 = (lane & 15) * 4;
#pragma unroll 1
  for (int m = 0; m < 16; ++m) {
    const int src = m * 4 + (lane >> 4);
    const float soa = __shfl(oa, src);
    const float sob = __shfl(ob, src);
    const int   si1 = __shfl(i1, src);
    const int   si2 = __shfl(i2, src);
    f32x4 v;
    v.x = (e0 + 0 == si1) ? soa : ((e0 + 0 == si2) ? sob : 0.0f);
    v.y = (e0 + 1 == si1) ? soa : ((e0 + 1 == si2) ? sob : 0.0f);
    v.z = (e0 + 2 == si1) ? soa : ((e0 + 2 == si2) ? sob : 0.0f);
    v.w = (e0 + 3 == si1) ? soa : ((e0 + 3 == si2) ? sob : 0.0f);
    const long tok = twbase + m * 4 + (lane >> 4);  // this lane's token
    if (tok < n) {
      f32x4* dst = reinterpret_cast<f32x4*>(out + (twbase + m * 4) * NE) + lane;
      *dst = v;
    }
  }
}

extern "C" void kernel_launch(void* const* d_in, const int* in_sizes, int n_in,
                              void* d_out, int out_size, void* d_ws, size_t ws_size,
                              hipStream_t stream) {
  const float* x  = (const float*)d_in[0];
  const float* W1 = (const float*)d_in[1];
  const float* b1 = (const float*)d_in[2];
  const float* W2 = (const float*)d_in[3];
  const float* b2 = (const float*)d_in[4];
  float* out = (float*)d_out;
  const int n_tokens = in_sizes[0] / DIM_IN;
  const int grid = (n_tokens + BLOCK - 1) / BLOCK;
  hipLaunchKernelGGL(router_fwd, dim3(grid), dim3(BLOCK), 0, stream,
                     x, W1, b1, W2, b2, out, n_tokens);
}